// Round 13
// baseline (554.200 us; speedup 1.0000x reference)
//
#include <hip/hip_runtime.h>

#define BB 16
#define NN 2048
#define MM 2048
#define EPSF 1e-9f
#define SKIPT (-135.0f)   // exp2(arg) == 0 below this

typedef float v2f __attribute__((ext_vector_type(2)));

constexpr int CH = 64;     // stream chunk length (2 outputs/thread)
// grid: BB batches x 4 groups(512 own-points) x 32 chunks = 2048 blocks
// Ping-pong parity identical to R8-R12 scheme. Points are Morton-sorted per
// batch at init (output is permutation-invariant: all reductions are complete
// sums; state arrays live consistently in permuted space).

// ---------------- init ----------------
__global__ __launch_bounds__(256) void init_kernel(
    const float* __restrict__ xyz1, const float* __restrict__ xyz2,
    float4* __restrict__ P1, float4* __restrict__ P2,
    float* __restrict__ remR0,
    float* __restrict__ stRS, float* __restrict__ stU,
    float* __restrict__ stS, float* __restrict__ stT,
    float* __restrict__ out)
{
    const int t = blockIdx.x * 256 + threadIdx.x;   // 0 .. BB*NN-1
    if (t < BB * NN) {
        P1[t] = make_float4(xyz1[3*t+0], xyz1[3*t+1], xyz1[3*t+2], 0.0f);
        stRS[t] = 0.0f; stRS[BB*NN + t] = 0.0f;
        stU[t]  = 0.0f; stU[BB*NN + t]  = 0.0f;
    }
    if (t < BB * MM) {
        P2[t] = make_float4(xyz2[3*t+0], xyz2[3*t+1], xyz2[3*t+2], 0.0f);
        remR0[t] = 1.0f;
        stS[t] = 0.0f; stS[BB*MM + t] = 0.0f;
        stT[t] = 0.0f; stT[BB*MM + t] = 0.0f;
    }
    if (t < BB) out[t] = 0.0f;
}

// ---------------- Morton sort (per batch, in-place permute of P1 or P2) ----------------
__device__ inline unsigned mortonExpand(unsigned v) {   // 10 bits -> every 3rd bit
    v = (v | (v << 16)) & 0x030000FFu;
    v = (v | (v << 8))  & 0x0300F00Fu;
    v = (v | (v << 4))  & 0x030C30C3u;
    v = (v | (v << 2))  & 0x09249249u;
    return v;
}

__global__ __launch_bounds__(1024) void sortK(float4* __restrict__ P1,
                                              float4* __restrict__ P2)
{
    __shared__ unsigned long long keys[2048];   // 16 KB: (morton<<32)|idx
    __shared__ float4 pts[2048];                // 32 KB
    const int batch = blockIdx.x & 15;
    float4* P = (blockIdx.x >> 4) ? (P2 + batch * MM) : (P1 + batch * NN);
    const int tid = threadIdx.x;

#pragma unroll
    for (int r = 0; r < 2; ++r) {
        const int i = tid + r * 1024;
        const float4 p = P[i];
        pts[i] = p;
        const unsigned qx = (unsigned)fminf(fmaxf((p.x + 4.0f) * 128.0f, 0.0f), 1023.0f);
        const unsigned qy = (unsigned)fminf(fmaxf((p.y + 4.0f) * 128.0f, 0.0f), 1023.0f);
        const unsigned qz = (unsigned)fminf(fmaxf((p.z + 4.0f) * 128.0f, 0.0f), 1023.0f);
        const unsigned code = mortonExpand(qx) | (mortonExpand(qy) << 1)
                            | (mortonExpand(qz) << 2);
        keys[i] = ((unsigned long long)code << 32) | (unsigned)i;
    }

    for (int k = 2; k <= 2048; k <<= 1) {
        for (int j = k >> 1; j > 0; j >>= 1) {
            __syncthreads();
#pragma unroll
            for (int r = 0; r < 2; ++r) {
                const int i = tid + r * 1024;
                const int ixj = i ^ j;
                if (ixj > i) {
                    const bool up = ((i & k) == 0);
                    const unsigned long long a = keys[i], b = keys[ixj];
                    if ((a > b) == up) { keys[i] = b; keys[ixj] = a; }
                }
            }
        }
    }
    __syncthreads();
#pragma unroll
    for (int r = 0; r < 2; ++r) {
        const int i = tid + r * 1024;
        P[i] = pts[(unsigned)keys[i]];          // low 32 bits = original idx
    }
}

// ---------------- rowInit: stRS[1] += sum_l exp(coef0*d2) (remR=1) ----------------
__global__ __launch_bounds__(256) void rowInit(
    const float4* __restrict__ P1, const float4* __restrict__ P2,
    float* __restrict__ stRSacc, float coef)
{
    __shared__ float4 sCol[CH];
    const int chunks = MM / CH;                   // 32
    const int bpb = (NN / 512) * chunks;          // 128
    const int batch = blockIdx.x / bpb;
    const int rem   = blockIdx.x % bpb;
    const int rg    = rem / chunks;
    const int ic    = rem % chunks;
    const int t     = threadIdx.x;

    if (t < CH) sCol[t] = P2[batch * MM + ic * CH + t];
    __syncthreads();

    const int row0 = batch * NN + rg * 512 + t;
    const int row1 = row0 + 256;
    const float4 p0 = P1[row0];
    const float4 p1 = P1[row1];
    const v2f px = {p0.x, p1.x}, py = {p0.y, p1.y}, pz = {p0.z, p1.z};
    v2f rs = {0.0f, 0.0f};
#pragma unroll 4
    for (int ii = 0; ii < CH; ++ii) {
        const float4 q = sCol[ii];
        const v2f dx = px - q.x, dy = py - q.y, dz = pz - q.z;
        const v2f g = coef * (dx*dx + dy*dy + dz*dz);
        if (__ballot((g.x > SKIPT) || (g.y > SKIPT))) {
            v2f e;
            e.x = __builtin_amdgcn_exp2f(g.x);
            e.y = __builtin_amdgcn_exp2f(g.y);
            rs += e;
        }
    }
    atomicAdd(&stRSacc[row0], rs.x);
    atomicAdd(&stRSacc[row1], rs.y);
}

// ---------------- colK: row-finalize prelude + column-partial stream ----------------
// MODE 0: j==0 (remL=1). MODE 1: general. MODE 2: j==9 (coef==0 -> e=scale).
template<int MODE, bool SPARSE>
__global__ __launch_bounds__(256) void colK(
    const float4* __restrict__ P1, const float4* __restrict__ P2,
    const float* __restrict__ stRSr, const float* __restrict__ stUr,
    float* __restrict__ stRSz, float* __restrict__ stUz,
    const float* __restrict__ remLr, float* __restrict__ remLw,
    const float* __restrict__ scaler, float* __restrict__ scalew,
    float* __restrict__ stS, float* __restrict__ stT,
    float coef)
{
    __shared__ float4 sRow[CH];                   // x1,y1,z1,scale_j
    const int chunks = NN / CH;                   // 32
    const int bpb = (MM / 512) * chunks;          // 128
    const int batch = blockIdx.x / bpb;
    const int rem   = blockIdx.x % bpb;
    const int cg    = rem / chunks;
    const int ic    = rem % chunks;
    const int t     = threadIdx.x;

    // prelude: finalize rows of this chunk (duplicated by 4 cg-blocks; identical values)
    if (t < CH) {
        const int gi = batch * NN + ic * CH + t;
        float L;
        if (MODE == 0) L = 1.0f;
        else           L = fmaxf(remLr[gi] - scaler[gi] * stUr[gi], 0.0f);
        remLw[gi] = L;
        const float sc = L / (stRSr[gi] + EPSF);
        scalew[gi] = sc;
        const float4 p = P1[gi];
        sRow[t] = make_float4(p.x, p.y, p.z, sc);
        stRSz[gi] = 0.0f; stUz[gi] = 0.0f;        // zero next accumulation parity
    }
    __syncthreads();

    const int col0 = batch * MM + cg * 512 + t;
    const int col1 = col0 + 256;
    const float4 q0 = P2[col0];
    const float4 q1 = P2[col1];
    const v2f qx = {q0.x, q1.x}, qy = {q0.y, q1.y}, qz = {q0.z, q1.z};
    v2f s = {0.0f, 0.0f}, tt = {0.0f, 0.0f};
#pragma unroll 4
    for (int ii = 0; ii < CH; ++ii) {
        const float4 a = sRow[ii];
        const v2f dx = a.x - qx, dy = a.y - qy, dz = a.z - qz;
        const v2f d2 = dx*dx + dy*dy + dz*dz;
        if (SPARSE) {
            const v2f g = coef * d2;
            if (__ballot((g.x > SKIPT) || (g.y > SKIPT))) {
                v2f e;
                e.x = __builtin_amdgcn_exp2f(g.x);
                e.y = __builtin_amdgcn_exp2f(g.y);
                e *= a.w;
                v2f sq;
                sq.x = __builtin_amdgcn_sqrtf(d2.x);
                sq.y = __builtin_amdgcn_sqrtf(d2.y);
                s += e;
                tt += e * sq;
            }
        } else {
            v2f e;
            if (MODE == 2) { e.x = a.w; e.y = a.w; }
            else {
                const v2f g = coef * d2;
                e.x = a.w * __builtin_amdgcn_exp2f(g.x);
                e.y = a.w * __builtin_amdgcn_exp2f(g.y);
            }
            v2f sq;
            sq.x = __builtin_amdgcn_sqrtf(d2.x);
            sq.y = __builtin_amdgcn_sqrtf(d2.y);
            s += e;
            tt += e * sq;
        }
    }
    atomicAdd(&stS[col0], s.x);
    atomicAdd(&stT[col0], tt.x);
    atomicAdd(&stS[col1], s.y);
    atomicAdd(&stT[col1], tt.y);
}

// ---------------- rowK: col-finalize prelude + row-partial stream ----------------
// MODE 1: general. MODE 2: j==8 (rs = sum remR_9, u at coefP direct).
template<int MODE, bool SPARSE>
__global__ __launch_bounds__(256) void rowK(
    const float4* __restrict__ P1, const float4* __restrict__ P2,
    const float* __restrict__ stSr, const float* __restrict__ stTr,
    float* __restrict__ stSz, float* __restrict__ stTz,
    const float* __restrict__ remRr, float* __restrict__ remRw,
    float* __restrict__ stRS, float* __restrict__ stU,
    float* __restrict__ out,
    float coefP, float coefN)
{
    __shared__ float4 sCol[CH];                   // x2,y2,z2,remR_{j+1}
    __shared__ float  sPc[CH];                    // Pcol_j
    const int chunks = MM / CH;                   // 32
    const int bpb = (NN / 512) * chunks;          // 128
    const int batch = blockIdx.x / bpb;
    const int rem   = blockIdx.x % bpb;
    const int rg    = rem / chunks;
    const int ic    = rem % chunks;
    const int t     = threadIdx.x;

    // prelude: finalize cols of this chunk (duplicated by 4 rg-blocks; identical values)
    float c = 0.0f;
    if (t < CH) {
        const int gl = batch * MM + ic * CH + t;
        const float R  = remRr[gl];
        const float s  = stSr[gl];
        const float t2 = stTr[gl];
        const float sumr = s * R;
        const float cons = fminf(R / (sumr + EPSF), 1.0f);
        const float pcol = R * cons;
        const float Rn   = fmaxf(R - sumr * cons, 0.0f);
        remRw[gl] = Rn;
        const float4 p = P2[gl];
        sCol[t] = make_float4(p.x, p.y, p.z, Rn);
        sPc[t]  = pcol;
        stSz[gl] = 0.0f; stTz[gl] = 0.0f;         // zero next accumulation parity
        if (rg == 0) c = pcol * t2;               // cost contribution (once per chunk)
    }
    if (rg == 0) {
#pragma unroll
        for (int off = 32; off > 0; off >>= 1) c += __shfl_xor(c, off, 64);
        if (t < CH && (t & 63) == 0) atomicAdd(out + batch, c);
    }
    __syncthreads();

    const int row0 = batch * NN + rg * 512 + t;
    const int row1 = row0 + 256;
    const float4 p0 = P1[row0];
    const float4 p1 = P1[row1];
    const v2f px = {p0.x, p1.x}, py = {p0.y, p1.y}, pz = {p0.z, p1.z};
    v2f rs = {0.0f, 0.0f}, u = {0.0f, 0.0f};
#pragma unroll 4
    for (int ii = 0; ii < CH; ++ii) {
        const float4 q = sCol[ii];
        const float pc = sPc[ii];
        const v2f dx = px - q.x, dy = py - q.y, dz = pz - q.z;
        const v2f d2 = dx*dx + dy*dy + dz*dz;
        if (MODE == 1) {
            const v2f g = coefN * d2;
            if (SPARSE) {
                if (__ballot((g.x > SKIPT) || (g.y > SKIPT))) {
                    v2f en;
                    en.x = __builtin_amdgcn_exp2f(g.x);
                    en.y = __builtin_amdgcn_exp2f(g.y);
                    const v2f e2 = en * en;
                    const v2f e4 = e2 * e2;
                    u  += e4 * pc;                // e_prev = e_next^4
                    rs += en * q.w;
                }
            } else {
                v2f en;
                en.x = __builtin_amdgcn_exp2f(g.x);
                en.y = __builtin_amdgcn_exp2f(g.y);
                const v2f e2 = en * en;
                const v2f e4 = e2 * e2;
                u  += e4 * pc;
                rs += en * q.w;
            }
        } else {
            const v2f g = coefP * d2;
            v2f ep;
            ep.x = __builtin_amdgcn_exp2f(g.x);
            ep.y = __builtin_amdgcn_exp2f(g.y);
            u  += ep * pc;
            rs += q.w;                            // e_next = exp(0) = 1
        }
    }
    atomicAdd(&stRS[row0], rs.x);
    atomicAdd(&stU[row0], u.x);
    atomicAdd(&stRS[row1], rs.y);
    atomicAdd(&stU[row1], u.y);
}

// ---------------- finCost: cost for level 9 (no state updates) ----------------
__global__ __launch_bounds__(256) void finCost(
    const float* __restrict__ stSr, const float* __restrict__ stTr,
    const float* __restrict__ remRr, float* __restrict__ out)
{
    const int idx = blockIdx.x * 256 + threadIdx.x;
    const int batch = idx / MM;
    const float R = remRr[idx];
    const float sumr = stSr[idx] * R;
    const float cons = fminf(R / (sumr + EPSF), 1.0f);
    float c = R * cons * stTr[idx];
#pragma unroll
    for (int off = 32; off > 0; off >>= 1) c += __shfl_xor(c, off, 64);
    if ((threadIdx.x & 63) == 0) atomicAdd(out + batch, c);
}

extern "C" void kernel_launch(void* const* d_in, const int* in_sizes, int n_in,
                              void* d_out, int out_size, void* d_ws, size_t ws_size,
                              hipStream_t stream)
{
    const float* xyz1 = (const float*)d_in[0];
    const float* xyz2 = (const float*)d_in[1];
    float* out = (float*)d_out;

    const int BN = BB * NN, BM = BB * MM;
    float4* P1 = (float4*)d_ws;
    float4* P2 = P1 + BN;
    float* remL  = (float*)(P2 + BM);       // [2][BN]
    float* scale = remL + 2 * BN;           // [2][BN]
    float* remR  = scale + 2 * BN;          // [2][BM]
    float* stRS  = remR + 2 * BM;           // [2][BN]
    float* stU   = stRS + 2 * BN;           // [2][BN]
    float* stS   = stU + 2 * BN;            // [2][BM]
    float* stT   = stS + 2 * BM;            // [2][BM]

    init_kernel<<<dim3(BN / 256), dim3(256), 0, stream>>>(
        xyz1, xyz2, P1, P2, remR, stRS, stU, stS, stT, out);

    // Morton-sort both point sets per batch (permutation-invariant output)
    sortK<<<dim3(32), dim3(1024), 0, stream>>>(P1, P2);

    // levels: j = 7..-1 -> -(4^j), then 0.  coef = level * log2(e)
    float coef[10];
    const double lv[10] = {-16384.0, -4096.0, -1024.0, -256.0, -64.0,
                           -16.0, -4.0, -1.0, -0.25, 0.0};
    for (int i = 0; i < 10; ++i) coef[i] = (float)(lv[i] * 1.4426950408889634);

    dim3 grid(BB * 4 * (NN / CH));          // 16*4*32 = 2048
    dim3 fgrid(BM / 256);                   // 128
    dim3 blk(256);

    rowInit<<<grid, blk, 0, stream>>>(P1, P2, stRS + 1 * BN, coef[0]);

    for (int j = 0; j < 10; ++j) {
        const int p = j & 1, q = 1 - p;
        if (j == 0)
            colK<0, true><<<grid, blk, 0, stream>>>(P1, P2,
                stRS + q*BN, stU + q*BN, stRS + p*BN, stU + p*BN,
                remL + p*BN, remL + q*BN, scale + p*BN, scale + q*BN,
                stS + p*BM, stT + p*BM, coef[0]);
        else if (j <= 5)
            colK<1, true><<<grid, blk, 0, stream>>>(P1, P2,
                stRS + q*BN, stU + q*BN, stRS + p*BN, stU + p*BN,
                remL + p*BN, remL + q*BN, scale + p*BN, scale + q*BN,
                stS + p*BM, stT + p*BM, coef[j]);
        else if (j == 9)
            colK<2, false><<<grid, blk, 0, stream>>>(P1, P2,
                stRS + q*BN, stU + q*BN, stRS + p*BN, stU + p*BN,
                remL + p*BN, remL + q*BN, scale + p*BN, scale + q*BN,
                stS + p*BM, stT + p*BM, coef[9]);
        else
            colK<1, false><<<grid, blk, 0, stream>>>(P1, P2,
                stRS + q*BN, stU + q*BN, stRS + p*BN, stU + p*BN,
                remL + p*BN, remL + q*BN, scale + p*BN, scale + q*BN,
                stS + p*BM, stT + p*BM, coef[j]);

        if (j < 9) {
            if (j <= 4)
                rowK<1, true><<<grid, blk, 0, stream>>>(P1, P2,
                    stS + p*BM, stT + p*BM, stS + q*BM, stT + q*BM,
                    remR + p*BM, remR + q*BM,
                    stRS + p*BN, stU + p*BN, out, coef[j], coef[j+1]);
            else if (j < 8)
                rowK<1, false><<<grid, blk, 0, stream>>>(P1, P2,
                    stS + p*BM, stT + p*BM, stS + q*BM, stT + q*BM,
                    remR + p*BM, remR + q*BM,
                    stRS + p*BN, stU + p*BN, out, coef[j], coef[j+1]);
            else
                rowK<2, false><<<grid, blk, 0, stream>>>(P1, P2,
                    stS + p*BM, stT + p*BM, stS + q*BM, stT + q*BM,
                    remR + p*BM, remR + q*BM,
                    stRS + p*BN, stU + p*BN, out, coef[8], 0.0f);
        }
    }
    // level 9 cost: stS/stT parity 1, remR parity 1
    finCost<<<fgrid, blk, 0, stream>>>(stS + 1*BM, stT + 1*BM, remR + 1*BM, out);
}

// Round 14
// 531.987 us; speedup vs baseline: 1.0418x; 1.0418x over previous
//
#include <hip/hip_runtime.h>

#define BB 16
#define NN 2048
#define MM 2048
#define EPSF 1e-9f
#define SKIPT (-135.0f)   // exp2(arg) == 0 below this

typedef float v2f __attribute__((ext_vector_type(2)));

constexpr int CH = 32;     // stream chunk length (4 outputs/thread)
// grid: BB batches x 2 groups(1024 own-points) x 64 chunks = 2048 blocks
// Ping-pong parity identical to R8-R12 scheme.

// ---------------- init ----------------
__global__ __launch_bounds__(256) void init_kernel(
    const float* __restrict__ xyz1, const float* __restrict__ xyz2,
    float4* __restrict__ P1, float4* __restrict__ P2,
    float* __restrict__ remR0,
    float* __restrict__ stRS, float* __restrict__ stU,
    float* __restrict__ stS, float* __restrict__ stT,
    float* __restrict__ out)
{
    const int t = blockIdx.x * 256 + threadIdx.x;   // 0 .. BB*NN-1
    if (t < BB * NN) {
        P1[t] = make_float4(xyz1[3*t+0], xyz1[3*t+1], xyz1[3*t+2], 0.0f);
        stRS[t] = 0.0f; stRS[BB*NN + t] = 0.0f;
        stU[t]  = 0.0f; stU[BB*NN + t]  = 0.0f;
    }
    if (t < BB * MM) {
        P2[t] = make_float4(xyz2[3*t+0], xyz2[3*t+1], xyz2[3*t+2], 0.0f);
        remR0[t] = 1.0f;
        stS[t] = 0.0f; stS[BB*MM + t] = 0.0f;
        stT[t] = 0.0f; stT[BB*MM + t] = 0.0f;
    }
    if (t < BB) out[t] = 0.0f;
}

// ---------------- rowInit: stRS[1] += sum_l exp(coef0*d2) (remR=1) ----------------
__global__ __launch_bounds__(256) void rowInit(
    const float4* __restrict__ P1, const float4* __restrict__ P2,
    float* __restrict__ stRSacc, float coef)
{
    __shared__ float4 sCol[CH];
    const int chunks = MM / CH;                   // 64
    const int bpb = (NN / 1024) * chunks;         // 128
    const int batch = blockIdx.x / bpb;
    const int rem   = blockIdx.x % bpb;
    const int rg    = rem / chunks;
    const int ic    = rem % chunks;
    const int t     = threadIdx.x;

    if (t < CH) sCol[t] = P2[batch * MM + ic * CH + t];
    __syncthreads();

    const int r0 = batch * NN + rg * 1024 + t;
    const float4 pa = P1[r0];
    const float4 pb = P1[r0 + 256];
    const float4 pc_ = P1[r0 + 512];
    const float4 pd = P1[r0 + 768];
    const v2f px0 = {pa.x, pb.x}, py0 = {pa.y, pb.y}, pz0 = {pa.z, pb.z};
    const v2f px1 = {pc_.x, pd.x}, py1 = {pc_.y, pd.y}, pz1 = {pc_.z, pd.z};
    v2f rs0 = {0.0f, 0.0f}, rs1 = {0.0f, 0.0f};
#pragma unroll 4
    for (int ii = 0; ii < CH; ++ii) {
        const float4 q = sCol[ii];
        const v2f dx0 = px0 - q.x, dy0 = py0 - q.y, dz0 = pz0 - q.z;
        const v2f dx1 = px1 - q.x, dy1 = py1 - q.y, dz1 = pz1 - q.z;
        const v2f g0 = coef * (dx0*dx0 + dy0*dy0 + dz0*dz0);
        const v2f g1 = coef * (dx1*dx1 + dy1*dy1 + dz1*dz1);
        if (__ballot((g0.x > SKIPT) || (g0.y > SKIPT) ||
                     (g1.x > SKIPT) || (g1.y > SKIPT))) {
            v2f e0, e1;
            e0.x = __builtin_amdgcn_exp2f(g0.x);
            e0.y = __builtin_amdgcn_exp2f(g0.y);
            e1.x = __builtin_amdgcn_exp2f(g1.x);
            e1.y = __builtin_amdgcn_exp2f(g1.y);
            rs0 += e0; rs1 += e1;
        }
    }
    atomicAdd(&stRSacc[r0],       rs0.x);
    atomicAdd(&stRSacc[r0 + 256], rs0.y);
    atomicAdd(&stRSacc[r0 + 512], rs1.x);
    atomicAdd(&stRSacc[r0 + 768], rs1.y);
}

// ---------------- colK: row-finalize prelude + column-partial stream ----------------
// MODE 0: j==0 (remL=1). MODE 1: general. MODE 2: j==9 (coef==0 -> e=scale).
template<int MODE, bool SPARSE>
__global__ __launch_bounds__(256) void colK(
    const float4* __restrict__ P1, const float4* __restrict__ P2,
    const float* __restrict__ stRSr, const float* __restrict__ stUr,
    float* __restrict__ stRSz, float* __restrict__ stUz,
    const float* __restrict__ remLr, float* __restrict__ remLw,
    const float* __restrict__ scaler, float* __restrict__ scalew,
    float* __restrict__ stS, float* __restrict__ stT,
    float coef)
{
    __shared__ float4 sRow[CH];                   // x1,y1,z1,scale_j
    const int chunks = NN / CH;                   // 64
    const int bpb = (MM / 1024) * chunks;         // 128
    const int batch = blockIdx.x / bpb;
    const int rem   = blockIdx.x % bpb;
    const int cg    = rem / chunks;
    const int ic    = rem % chunks;
    const int t     = threadIdx.x;

    // prelude: finalize rows of this chunk (duplicated by 2 cg-blocks; identical values)
    if (t < CH) {
        const int gi = batch * NN + ic * CH + t;
        float L;
        if (MODE == 0) L = 1.0f;
        else           L = fmaxf(remLr[gi] - scaler[gi] * stUr[gi], 0.0f);
        remLw[gi] = L;
        const float sc = L / (stRSr[gi] + EPSF);
        scalew[gi] = sc;
        const float4 p = P1[gi];
        sRow[t] = make_float4(p.x, p.y, p.z, sc);
        stRSz[gi] = 0.0f; stUz[gi] = 0.0f;        // zero next accumulation parity
    }
    __syncthreads();

    const int c0 = batch * MM + cg * 1024 + t;
    const float4 qa = P2[c0];
    const float4 qb = P2[c0 + 256];
    const float4 qc = P2[c0 + 512];
    const float4 qd = P2[c0 + 768];
    const v2f qx0 = {qa.x, qb.x}, qy0 = {qa.y, qb.y}, qz0 = {qa.z, qb.z};
    const v2f qx1 = {qc.x, qd.x}, qy1 = {qc.y, qd.y}, qz1 = {qc.z, qd.z};
    v2f s0 = {0.0f, 0.0f}, t0 = {0.0f, 0.0f};
    v2f s1 = {0.0f, 0.0f}, t1 = {0.0f, 0.0f};
#pragma unroll 4
    for (int ii = 0; ii < CH; ++ii) {
        const float4 a = sRow[ii];
        const v2f dx0 = a.x - qx0, dy0 = a.y - qy0, dz0 = a.z - qz0;
        const v2f dx1 = a.x - qx1, dy1 = a.y - qy1, dz1 = a.z - qz1;
        const v2f d20 = dx0*dx0 + dy0*dy0 + dz0*dz0;
        const v2f d21 = dx1*dx1 + dy1*dy1 + dz1*dz1;
        if (SPARSE) {
            const v2f g0 = coef * d20, g1 = coef * d21;
            if (__ballot((g0.x > SKIPT) || (g0.y > SKIPT) ||
                         (g1.x > SKIPT) || (g1.y > SKIPT))) {
                v2f e0, e1, sq0, sq1;
                e0.x = __builtin_amdgcn_exp2f(g0.x);
                e0.y = __builtin_amdgcn_exp2f(g0.y);
                e1.x = __builtin_amdgcn_exp2f(g1.x);
                e1.y = __builtin_amdgcn_exp2f(g1.y);
                e0 *= a.w; e1 *= a.w;
                sq0.x = __builtin_amdgcn_sqrtf(d20.x);
                sq0.y = __builtin_amdgcn_sqrtf(d20.y);
                sq1.x = __builtin_amdgcn_sqrtf(d21.x);
                sq1.y = __builtin_amdgcn_sqrtf(d21.y);
                s0 += e0; s1 += e1;
                t0 += e0 * sq0; t1 += e1 * sq1;
            }
        } else {
            v2f e0, e1, sq0, sq1;
            if (MODE == 2) { e0.x = a.w; e0.y = a.w; e1.x = a.w; e1.y = a.w; }
            else {
                const v2f g0 = coef * d20, g1 = coef * d21;
                e0.x = a.w * __builtin_amdgcn_exp2f(g0.x);
                e0.y = a.w * __builtin_amdgcn_exp2f(g0.y);
                e1.x = a.w * __builtin_amdgcn_exp2f(g1.x);
                e1.y = a.w * __builtin_amdgcn_exp2f(g1.y);
            }
            sq0.x = __builtin_amdgcn_sqrtf(d20.x);
            sq0.y = __builtin_amdgcn_sqrtf(d20.y);
            sq1.x = __builtin_amdgcn_sqrtf(d21.x);
            sq1.y = __builtin_amdgcn_sqrtf(d21.y);
            s0 += e0; s1 += e1;
            t0 += e0 * sq0; t1 += e1 * sq1;
        }
    }
    atomicAdd(&stS[c0],       s0.x);
    atomicAdd(&stT[c0],       t0.x);
    atomicAdd(&stS[c0 + 256], s0.y);
    atomicAdd(&stT[c0 + 256], t0.y);
    atomicAdd(&stS[c0 + 512], s1.x);
    atomicAdd(&stT[c0 + 512], t1.x);
    atomicAdd(&stS[c0 + 768], s1.y);
    atomicAdd(&stT[c0 + 768], t1.y);
}

// ---------------- rowK: col-finalize prelude + row-partial stream ----------------
// MODE 1: general. MODE 2: j==8 (rs = sum remR_9, u at coefP direct).
template<int MODE, bool SPARSE>
__global__ __launch_bounds__(256) void rowK(
    const float4* __restrict__ P1, const float4* __restrict__ P2,
    const float* __restrict__ stSr, const float* __restrict__ stTr,
    float* __restrict__ stSz, float* __restrict__ stTz,
    const float* __restrict__ remRr, float* __restrict__ remRw,
    float* __restrict__ stRS, float* __restrict__ stU,
    float* __restrict__ out,
    float coefP, float coefN)
{
    __shared__ float4 sCol[CH];                   // x2,y2,z2,remR_{j+1}
    __shared__ float  sPc[CH];                    // Pcol_j
    const int chunks = MM / CH;                   // 64
    const int bpb = (NN / 1024) * chunks;         // 128
    const int batch = blockIdx.x / bpb;
    const int rem   = blockIdx.x % bpb;
    const int rg    = rem / chunks;
    const int ic    = rem % chunks;
    const int t     = threadIdx.x;

    // prelude: finalize cols of this chunk (duplicated by 2 rg-blocks; identical values)
    float c = 0.0f;
    if (t < CH) {
        const int gl = batch * MM + ic * CH + t;
        const float R  = remRr[gl];
        const float s  = stSr[gl];
        const float t2 = stTr[gl];
        const float sumr = s * R;
        const float cons = fminf(R / (sumr + EPSF), 1.0f);
        const float pcol = R * cons;
        const float Rn   = fmaxf(R - sumr * cons, 0.0f);
        remRw[gl] = Rn;
        const float4 p = P2[gl];
        sCol[t] = make_float4(p.x, p.y, p.z, Rn);
        sPc[t]  = pcol;
        stSz[gl] = 0.0f; stTz[gl] = 0.0f;         // zero next accumulation parity
        if (rg == 0) c = pcol * t2;               // cost contribution (once per chunk)
    }
    if (rg == 0) {
#pragma unroll
        for (int off = 32; off > 0; off >>= 1) c += __shfl_xor(c, off, 64);
        if (t == 0) atomicAdd(out + batch, c);
    }
    __syncthreads();

    const int r0 = batch * NN + rg * 1024 + t;
    const float4 pa = P1[r0];
    const float4 pb = P1[r0 + 256];
    const float4 pc_ = P1[r0 + 512];
    const float4 pd = P1[r0 + 768];
    const v2f px0 = {pa.x, pb.x}, py0 = {pa.y, pb.y}, pz0 = {pa.z, pb.z};
    const v2f px1 = {pc_.x, pd.x}, py1 = {pc_.y, pd.y}, pz1 = {pc_.z, pd.z};
    v2f rs0 = {0.0f, 0.0f}, u0 = {0.0f, 0.0f};
    v2f rs1 = {0.0f, 0.0f}, u1 = {0.0f, 0.0f};
#pragma unroll 4
    for (int ii = 0; ii < CH; ++ii) {
        const float4 q = sCol[ii];
        const float pc = sPc[ii];
        const v2f dx0 = px0 - q.x, dy0 = py0 - q.y, dz0 = pz0 - q.z;
        const v2f dx1 = px1 - q.x, dy1 = py1 - q.y, dz1 = pz1 - q.z;
        const v2f d20 = dx0*dx0 + dy0*dy0 + dz0*dz0;
        const v2f d21 = dx1*dx1 + dy1*dy1 + dz1*dz1;
        if (MODE == 1) {
            const v2f g0 = coefN * d20, g1 = coefN * d21;
            if (SPARSE) {
                if (__ballot((g0.x > SKIPT) || (g0.y > SKIPT) ||
                             (g1.x > SKIPT) || (g1.y > SKIPT))) {
                    v2f en0, en1;
                    en0.x = __builtin_amdgcn_exp2f(g0.x);
                    en0.y = __builtin_amdgcn_exp2f(g0.y);
                    en1.x = __builtin_amdgcn_exp2f(g1.x);
                    en1.y = __builtin_amdgcn_exp2f(g1.y);
                    const v2f e20 = en0 * en0, e21 = en1 * en1;
                    u0  += (e20 * e20) * pc;      // e_prev = e_next^4
                    u1  += (e21 * e21) * pc;
                    rs0 += en0 * q.w;
                    rs1 += en1 * q.w;
                }
            } else {
                v2f en0, en1;
                en0.x = __builtin_amdgcn_exp2f(g0.x);
                en0.y = __builtin_amdgcn_exp2f(g0.y);
                en1.x = __builtin_amdgcn_exp2f(g1.x);
                en1.y = __builtin_amdgcn_exp2f(g1.y);
                const v2f e20 = en0 * en0, e21 = en1 * en1;
                u0  += (e20 * e20) * pc;
                u1  += (e21 * e21) * pc;
                rs0 += en0 * q.w;
                rs1 += en1 * q.w;
            }
        } else {
            const v2f g0 = coefP * d20, g1 = coefP * d21;
            v2f ep0, ep1;
            ep0.x = __builtin_amdgcn_exp2f(g0.x);
            ep0.y = __builtin_amdgcn_exp2f(g0.y);
            ep1.x = __builtin_amdgcn_exp2f(g1.x);
            ep1.y = __builtin_amdgcn_exp2f(g1.y);
            u0  += ep0 * pc;
            u1  += ep1 * pc;
            rs0 += q.w;                           // e_next = exp(0) = 1
            rs1 += q.w;
        }
    }
    atomicAdd(&stRS[r0],       rs0.x);
    atomicAdd(&stU[r0],        u0.x);
    atomicAdd(&stRS[r0 + 256], rs0.y);
    atomicAdd(&stU[r0 + 256],  u0.y);
    atomicAdd(&stRS[r0 + 512], rs1.x);
    atomicAdd(&stU[r0 + 512],  u1.x);
    atomicAdd(&stRS[r0 + 768], rs1.y);
    atomicAdd(&stU[r0 + 768],  u1.y);
}

// ---------------- finCost: cost for level 9 (no state updates) ----------------
__global__ __launch_bounds__(256) void finCost(
    const float* __restrict__ stSr, const float* __restrict__ stTr,
    const float* __restrict__ remRr, float* __restrict__ out)
{
    const int idx = blockIdx.x * 256 + threadIdx.x;
    const int batch = idx / MM;
    const float R = remRr[idx];
    const float sumr = stSr[idx] * R;
    const float cons = fminf(R / (sumr + EPSF), 1.0f);
    float c = R * cons * stTr[idx];
#pragma unroll
    for (int off = 32; off > 0; off >>= 1) c += __shfl_xor(c, off, 64);
    if ((threadIdx.x & 63) == 0) atomicAdd(out + batch, c);
}

extern "C" void kernel_launch(void* const* d_in, const int* in_sizes, int n_in,
                              void* d_out, int out_size, void* d_ws, size_t ws_size,
                              hipStream_t stream)
{
    const float* xyz1 = (const float*)d_in[0];
    const float* xyz2 = (const float*)d_in[1];
    float* out = (float*)d_out;

    const int BN = BB * NN, BM = BB * MM;
    float4* P1 = (float4*)d_ws;
    float4* P2 = P1 + BN;
    float* remL  = (float*)(P2 + BM);       // [2][BN]
    float* scale = remL + 2 * BN;           // [2][BN]
    float* remR  = scale + 2 * BN;          // [2][BM]
    float* stRS  = remR + 2 * BM;           // [2][BN]
    float* stU   = stRS + 2 * BN;           // [2][BN]
    float* stS   = stU + 2 * BN;            // [2][BM]
    float* stT   = stS + 2 * BM;            // [2][BM]

    init_kernel<<<dim3(BN / 256), dim3(256), 0, stream>>>(
        xyz1, xyz2, P1, P2, remR, stRS, stU, stS, stT, out);

    // levels: j = 7..-1 -> -(4^j), then 0.  coef = level * log2(e)
    float coef[10];
    const double lv[10] = {-16384.0, -4096.0, -1024.0, -256.0, -64.0,
                           -16.0, -4.0, -1.0, -0.25, 0.0};
    for (int i = 0; i < 10; ++i) coef[i] = (float)(lv[i] * 1.4426950408889634);

    dim3 grid(BB * 2 * (NN / CH));          // 16*2*64 = 2048
    dim3 fgrid(BM / 256);                   // 128
    dim3 blk(256);

    rowInit<<<grid, blk, 0, stream>>>(P1, P2, stRS + 1 * BN, coef[0]);

    for (int j = 0; j < 10; ++j) {
        const int p = j & 1, q = 1 - p;
        if (j == 0)
            colK<0, true><<<grid, blk, 0, stream>>>(P1, P2,
                stRS + q*BN, stU + q*BN, stRS + p*BN, stU + p*BN,
                remL + p*BN, remL + q*BN, scale + p*BN, scale + q*BN,
                stS + p*BM, stT + p*BM, coef[0]);
        else if (j <= 3)
            colK<1, true><<<grid, blk, 0, stream>>>(P1, P2,
                stRS + q*BN, stU + q*BN, stRS + p*BN, stU + p*BN,
                remL + p*BN, remL + q*BN, scale + p*BN, scale + q*BN,
                stS + p*BM, stT + p*BM, coef[j]);
        else if (j == 9)
            colK<2, false><<<grid, blk, 0, stream>>>(P1, P2,
                stRS + q*BN, stU + q*BN, stRS + p*BN, stU + p*BN,
                remL + p*BN, remL + q*BN, scale + p*BN, scale + q*BN,
                stS + p*BM, stT + p*BM, coef[9]);
        else
            colK<1, false><<<grid, blk, 0, stream>>>(P1, P2,
                stRS + q*BN, stU + q*BN, stRS + p*BN, stU + p*BN,
                remL + p*BN, remL + q*BN, scale + p*BN, scale + q*BN,
                stS + p*BM, stT + p*BM, coef[j]);

        if (j < 9) {
            if (j <= 2)
                rowK<1, true><<<grid, blk, 0, stream>>>(P1, P2,
                    stS + p*BM, stT + p*BM, stS + q*BM, stT + q*BM,
                    remR + p*BM, remR + q*BM,
                    stRS + p*BN, stU + p*BN, out, coef[j], coef[j+1]);
            else if (j < 8)
                rowK<1, false><<<grid, blk, 0, stream>>>(P1, P2,
                    stS + p*BM, stT + p*BM, stS + q*BM, stT + q*BM,
                    remR + p*BM, remR + q*BM,
                    stRS + p*BN, stU + p*BN, out, coef[j], coef[j+1]);
            else
                rowK<2, false><<<grid, blk, 0, stream>>>(P1, P2,
                    stS + p*BM, stT + p*BM, stS + q*BM, stT + q*BM,
                    remR + p*BM, remR + q*BM,
                    stRS + p*BN, stU + p*BN, out, coef[8], 0.0f);
        }
    }
    // level 9 cost: stS/stT parity 1, remR parity 1
    finCost<<<fgrid, blk, 0, stream>>>(stS + 1*BM, stT + 1*BM, remR + 1*BM, out);
}